// Round 2
// baseline (1136.247 us; speedup 1.0000x reference)
//
#include <hip/hip_runtime.h>

// TriPlanePC2Encoder: scatter-mean of point features onto 3 canonical planes.
// B=8, N=200000, C=32, R=128. out[b, plane, c, row, col], plane order xy,yz,xz.
//
// Round 7: coarse row-bucketing + LDS fp32 accumulation (no full bin sort).
//   bin -> rowcount (128-bucket hist) -> rowscan (tiny) -> bucket (chunk-
//   reserving atomics, near-coalesced entry writes) -> transpose (feat ->
//   point-major bf16) -> accum (one block per (bp,row): LDS acc[128][32]
//   fp32 with diagonal skew, scattered 64B line reads with 4-deep MLP,
//   coalesced out writes).
// R6 lesson: global atomicAdd-with-return per point (4.8M, cross-XCD) is
// latency death (400us); here global atomics are 49K chunk reservations.
// ws overlay: bins (first 9.6MB) dead after bucket, so ftT (102.4MB)
// overlays it. Tail holds rowtot/rowoff/rowcur + ENT. WS_NEED unchanged.

constexpr int R     = 128;
constexpr int NBINS = R * R;        // 16384
constexpr int NPTS  = 200000;
constexpr int NB    = 8;
constexpr int NC    = 32;
constexpr int SPLIT = 16;           // tiles per (b,plane)
constexpr int TILE  = NPTS / SPLIT; // 12500

// ws layout:
//  phase1 (dead after bucket, overlaid by ftT later):
//    bins u16 [3][NB][NPTS]        @ 0           (9,600,000)
//  phase2: ftT bf16 [NB][NPTS][NC] @ 0           (102,400,000)
//  persistent tail:
//    rowtot u32 [24][128]          @ 102,400,000 (12,288)
//    rowoff u32 [24][129]          @ 102,416,384 (12,384)
//    rowcur u32 [24][128]          @ 102,432,768 (12,288)
//    ENT    u32 [24][NPTS]         @ 103,972,864 (19,200,000) end 123,172,864
constexpr size_t OFF_TOT    = 9600000;    // fallback-only cnt region
constexpr size_t OFF_ROWTOT = 102400000;
constexpr size_t OFF_ROWOFF = 102416384;
constexpr size_t OFF_ROWCUR = 102432768;
constexpr size_t OFF_ENT    = 103972864;
constexpr size_t WS_NEED    = 123172864;

__device__ __forceinline__ int coord_bin(float p) {
    // xyz_norm = (p+1)/2 - 0.5 ; then /(1+eps) + 0.5 ; clip ; *R ; trunc
    float v = (p + 1.0f) * 0.5f - 0.5f;
    float t = v / 1.00001f + 0.5f;                     // IEEE fp32 divide
    t = fminf(fmaxf(t, 0.0f), (float)(1.0 - 1e-5));
    return (int)(t * 128.0f);
}

__global__ __launch_bounds__(256) void bin_kernel(
    const float* __restrict__ xyz, unsigned short* __restrict__ bins) {
    int i = blockIdx.x * 256 + threadIdx.x;            // over B*N
    if (i >= NB * NPTS) return;
    float x = xyz[3 * (size_t)i + 0];
    float y = xyz[3 * (size_t)i + 1];
    float z = xyz[3 * (size_t)i + 2];
    int ix = coord_bin(x), iy = coord_bin(y), iz = coord_bin(z);
    // plane dims: xy=(0,1) yz=(1,2) xz=(0,2); lin = idx_d0 + R*idx_d1
    //   => col = idx_d0 (low 7 bits), row = idx_d1 (high 7 bits)
    bins[0 * (size_t)NB * NPTS + i] = (unsigned short)(ix + R * iy);
    bins[1 * (size_t)NB * NPTS + i] = (unsigned short)(iy + R * iz);
    bins[2 * (size_t)NB * NPTS + i] = (unsigned short)(ix + R * iz);
}

// Per-(bp,split) 128-bucket row histogram, flushed atomically (49K atomics).
__global__ __launch_bounds__(1024) void rowcount_kernel(
    const unsigned short* __restrict__ bins, unsigned* __restrict__ rowtot) {
    __shared__ unsigned h[128];
    int blk   = blockIdx.x;
    int split = blk & (SPLIT - 1);
    int bp    = blk >> 4;
    int b     = bp / 3, plane = bp - 3 * b;
    if (threadIdx.x < 128) h[threadIdx.x] = 0u;
    __syncthreads();
    const unsigned* src = (const unsigned*)(bins + ((size_t)plane * NB + b) * NPTS
                                                 + (size_t)split * TILE);
    for (int j = threadIdx.x; j < TILE / 2; j += 1024) {
        unsigned u = src[j];
        atomicAdd(&h[(u & 0xffffu) >> 7], 1u);
        atomicAdd(&h[u >> 23], 1u);                    // (u>>16)>>7
    }
    __syncthreads();
    if (threadIdx.x < 128) {
        unsigned v = h[threadIdx.x];
        if (v) atomicAdd(&rowtot[bp * 128 + threadIdx.x], v);
    }
}

// Per-bp exclusive scan of the 128 row counts; init rowcur = rowoff.
__global__ __launch_bounds__(128) void rowscan_kernel(
    const unsigned* __restrict__ rowtot, unsigned* __restrict__ rowoff,
    unsigned* __restrict__ rowcur) {
    __shared__ unsigned ts[128];
    int bp = blockIdx.x, t = threadIdx.x;
    unsigned v = rowtot[bp * 128 + t];
    ts[t] = v;
    __syncthreads();
    for (int o = 1; o < 128; o <<= 1) {                // Hillis-Steele incl.
        unsigned a = (t >= o) ? ts[t - o] : 0u;
        __syncthreads();
        ts[t] += a;
        __syncthreads();
    }
    unsigned excl = ts[t] - v;
    rowoff[bp * 129 + t] = excl;
    rowcur[bp * 128 + t] = excl;
    if (t == 127) rowoff[bp * 129 + 128] = ts[127];
}

// Bucket points by row. One chunk-reserving global atomic per (block,row);
// entry writes land in ~lcnt[row]*4B contiguous runs (near-coalesced).
// entry = (point_id << 7) | col   (n < 2^18, col < 128 -> 25 bits).
__global__ __launch_bounds__(1024) void bucket_kernel(
    const unsigned short* __restrict__ bins, unsigned* __restrict__ rowcur,
    unsigned* __restrict__ ENT) {
    __shared__ unsigned lcnt[128], lbase[128], lcur[128];
    int blk   = blockIdx.x;
    int split = blk & (SPLIT - 1);
    int bp    = blk >> 4;
    int b     = bp / 3, plane = bp - 3 * b;
    if (threadIdx.x < 128) { lcnt[threadIdx.x] = 0u; lcur[threadIdx.x] = 0u; }
    __syncthreads();
    const unsigned* src = (const unsigned*)(bins + ((size_t)plane * NB + b) * NPTS
                                                 + (size_t)split * TILE);
    for (int j = threadIdx.x; j < TILE / 2; j += 1024) {
        unsigned u = src[j];
        atomicAdd(&lcnt[(u & 0xffffu) >> 7], 1u);
        atomicAdd(&lcnt[u >> 23], 1u);
    }
    __syncthreads();
    if (threadIdx.x < 128)
        lbase[threadIdx.x] = atomicAdd(&rowcur[bp * 128 + threadIdx.x],
                                       lcnt[threadIdx.x]);
    __syncthreads();
    unsigned nbase = (unsigned)(split * TILE);
    unsigned* ep = ENT + (size_t)bp * NPTS;
    for (int j = threadIdx.x; j < TILE / 2; j += 1024) {
        unsigned u  = src[j];
        unsigned l0 = u & 0xffffu, l1 = u >> 16;
        unsigned r0 = l0 >> 7, c0 = l0 & 127u;
        unsigned r1 = l1 >> 7, c1 = l1 & 127u;
        unsigned p0 = lbase[r0] + atomicAdd(&lcur[r0], 1u);
        ep[p0] = ((nbase + 2u * j) << 7) | c0;
        unsigned p1 = lbase[r1] + atomicAdd(&lcur[r1], 1u);
        ep[p1] = ((nbase + 2u * j + 1u) << 7) | c1;
    }
}

// feat (b, C, N) fp32 -> ftT (b, n, c) bf16 (RNE). One point = 64 B line.
constexpr int TTILES = (NPTS + 255) / 256;   // 782
__global__ __launch_bounds__(256) void transpose_kernel(
    const float* __restrict__ feat, unsigned short* __restrict__ ftT) {
    int b = blockIdx.x / TTILES;
    int n = (blockIdx.x % TTILES) * 256 + threadIdx.x;
    if (n >= NPTS) return;
    const float* fb = feat + (size_t)b * NC * NPTS + n;
    unsigned pk[16];
#pragma unroll
    for (int c = 0; c < 16; ++c) {
        unsigned u0 = __float_as_uint(fb[(size_t)(2 * c) * NPTS]);
        unsigned u1 = __float_as_uint(fb[(size_t)(2 * c + 1) * NPTS]);
        unsigned r0 = (u0 + 0x7fffu + ((u0 >> 16) & 1u)) >> 16;   // bf16 RNE
        unsigned r1 = (u1 + 0x7fffu + ((u1 >> 16) & 1u)) >> 16;
        pk[c] = r0 | (r1 << 16);
    }
    uint4* dst = (uint4*)(ftT + ((size_t)b * NPTS + n) * NC);
#pragma unroll
    for (int q = 0; q < 4; ++q)
        dst[q] = make_uint4(pk[4 * q], pk[4 * q + 1], pk[4 * q + 2], pk[4 * q + 3]);
}

__device__ __forceinline__ float bf2f(unsigned short h) {
    return __uint_as_float((unsigned)h << 16);
}

// One block per (bp,row): accumulate ~1562 points into LDS acc[128 cols][32 ch]
// fp32 (diagonal skew -> conflict-free ds_add). 8 groups of 32 lanes; lane =
// channel; 4 points in flight per group. Coalesced epilogue stores.
__global__ __launch_bounds__(256) void accum_kernel(
    const unsigned* __restrict__ rowoff, const unsigned* __restrict__ ENT,
    const unsigned short* __restrict__ ftT, float* __restrict__ out) {
    __shared__ float acc[128 * NC];                    // 16 KB
    __shared__ unsigned cnt[128];
    int bp = blockIdx.x >> 7;
    int r  = blockIdx.x & 127;
    int b  = bp / 3;
    for (int i = threadIdx.x; i < 128 * NC; i += 256) acc[i] = 0.0f;
    if (threadIdx.x < 128) cnt[threadIdx.x] = 0u;
    __syncthreads();
    unsigned s = rowoff[bp * 129 + r], e = rowoff[bp * 129 + r + 1];
    int g = threadIdx.x >> 5, c = threadIdx.x & 31;
    const unsigned* ep = ENT + (size_t)bp * NPTS;
    const unsigned short* fb = ftT + (size_t)b * NPTS * NC + c;
    unsigned i = s + (unsigned)g;
    for (; i + 24 < e; i += 32) {                      // 4 pts/group in flight
        unsigned e0 = ep[i], e1 = ep[i + 8], e2 = ep[i + 16], e3 = ep[i + 24];
        float v0 = bf2f(fb[(size_t)(e0 >> 7) * NC]);
        float v1 = bf2f(fb[(size_t)(e1 >> 7) * NC]);
        float v2 = bf2f(fb[(size_t)(e2 >> 7) * NC]);
        float v3 = bf2f(fb[(size_t)(e3 >> 7) * NC]);
        unsigned c0 = e0 & 127u, c1 = e1 & 127u, c2 = e2 & 127u, c3 = e3 & 127u;
        atomicAdd(&acc[c0 * NC + ((c + c0) & 31)], v0);
        atomicAdd(&acc[c1 * NC + ((c + c1) & 31)], v1);
        atomicAdd(&acc[c2 * NC + ((c + c2) & 31)], v2);
        atomicAdd(&acc[c3 * NC + ((c + c3) & 31)], v3);
        if (c == 0) {
            atomicAdd(&cnt[c0], 1u); atomicAdd(&cnt[c1], 1u);
            atomicAdd(&cnt[c2], 1u); atomicAdd(&cnt[c3], 1u);
        }
    }
    for (; i < e; i += 8) {
        unsigned e0 = ep[i];
        float v0 = bf2f(fb[(size_t)(e0 >> 7) * NC]);
        unsigned c0 = e0 & 127u;
        atomicAdd(&acc[c0 * NC + ((c + c0) & 31)], v0);
        if (c == 0) atomicAdd(&cnt[c0], 1u);
    }
    __syncthreads();
    // out[bp][cc][r][col]; threads: col = tid&127 -> 512B contiguous stores
    int co  = threadIdx.x >> 7;                        // 0..1
    int col = threadIdx.x & 127;
    float inv = 1.0f / fmaxf((float)cnt[col], 1.0f);   // empty bins -> 0
    float* ob = out + (size_t)bp * NC * NBINS + (size_t)r * 128 + col;
    for (int cc = co; cc < NC; cc += 2)
        ob[(size_t)cc * NBINS] = acc[col * NC + ((cc + col) & 31)] * inv;
}

// ---------- fallback (round-3 verified path; needs only bins + cnt) ----------
constexpr int CHUNKS = NPTS / 8;
__global__ __launch_bounds__(1024) void count_fb_kernel(
    const unsigned short* __restrict__ bins, unsigned* __restrict__ cnt) {
    __shared__ unsigned hist[NBINS];
    int blk   = blockIdx.x;
    int split = blk & (SPLIT - 1);
    int bp    = blk >> 4;
    int b     = bp / 3, plane = bp - 3 * b;
    for (int i = threadIdx.x; i < NBINS; i += 1024) hist[i] = 0u;
    __syncthreads();
    const unsigned short* src = bins + ((size_t)plane * NB + b) * NPTS
                                     + (size_t)split * TILE;
    for (int n = threadIdx.x; n < TILE; n += 1024) atomicAdd(&hist[src[n]], 1u);
    __syncthreads();
    unsigned* dst = cnt + (size_t)bp * NBINS;
    for (int i = threadIdx.x; i < NBINS; i += 1024) {
        unsigned v = hist[i];
        if (v) atomicAdd(&dst[i], v);
    }
}
__global__ __launch_bounds__(1024) void scatter_kernel(
    const unsigned short* __restrict__ bins, const float* __restrict__ feat,
    const unsigned* __restrict__ cnt, float* __restrict__ out) {
    __shared__ float hist[NBINS];
    int blk = blockIdx.x, b = blk / 96;
    int rem = blk - b * 96, plane = rem >> 5, ch = rem & 31;
    for (int i = threadIdx.x; i < NBINS; i += 1024) hist[i] = 0.0f;
    __syncthreads();
    const uint4*  bp4 = (const uint4*)(bins + ((size_t)plane * NB + b) * NPTS);
    const float4* fp4 = (const float4*)(feat + ((size_t)b * NC + ch) * NPTS);
    for (int p = threadIdx.x; p < CHUNKS; p += 1024) {
        uint4 bb = bp4[p];
        float4 f0 = fp4[2 * p], f1 = fp4[2 * p + 1];
        atomicAdd(&hist[bb.x & 0xffffu], f0.x);
        atomicAdd(&hist[bb.x >> 16],     f0.y);
        atomicAdd(&hist[bb.y & 0xffffu], f0.z);
        atomicAdd(&hist[bb.y >> 16],     f0.w);
        atomicAdd(&hist[bb.z & 0xffffu], f1.x);
        atomicAdd(&hist[bb.z >> 16],     f1.y);
        atomicAdd(&hist[bb.w & 0xffffu], f1.z);
        atomicAdd(&hist[bb.w >> 16],     f1.w);
    }
    __syncthreads();
    const unsigned* cb = cnt + (size_t)(b * 3 + plane) * NBINS;
    float* ob = out + (((size_t)b * 3 + plane) * NC + ch) * (size_t)NBINS;
    for (int i = threadIdx.x; i < NBINS; i += 1024)
        ob[i] = hist[i] / fmaxf((float)cb[i], 1.0f);
}

extern "C" void kernel_launch(void* const* d_in, const int* in_sizes, int n_in,
                              void* d_out, int out_size, void* d_ws, size_t ws_size,
                              hipStream_t stream) {
    const float* xyz  = (const float*)d_in[0];         // (B, N, 3)
    const float* feat = (const float*)d_in[1];         // (B, C, N)
    float* out = (float*)d_out;                        // (B, 3, C, R, R)
    char* ws = (char*)d_ws;
    unsigned short* bins = (unsigned short*)ws;

    int total_pts = NB * NPTS;
    bin_kernel<<<(total_pts + 255) / 256, 256, 0, stream>>>(xyz, bins);

    if (ws_size >= WS_NEED) {
        unsigned* rowtot = (unsigned*)(ws + OFF_ROWTOT);
        unsigned* rowoff = (unsigned*)(ws + OFF_ROWOFF);
        unsigned* rowcur = (unsigned*)(ws + OFF_ROWCUR);
        unsigned* ENT    = (unsigned*)(ws + OFF_ENT);
        unsigned short* ftT = (unsigned short*)ws;     // overlays bins
        hipMemsetAsync(rowtot, 0, (size_t)NB * 3 * 128 * sizeof(unsigned), stream);
        rowcount_kernel<<<NB * 3 * SPLIT, 1024, 0, stream>>>(bins, rowtot);
        rowscan_kernel<<<NB * 3, 128, 0, stream>>>(rowtot, rowoff, rowcur);
        bucket_kernel<<<NB * 3 * SPLIT, 1024, 0, stream>>>(bins, rowcur, ENT);
        transpose_kernel<<<NB * TTILES, 256, 0, stream>>>(feat, ftT);  // after bucket!
        accum_kernel<<<NB * 3 * 128, 256, 0, stream>>>(rowoff, ENT, ftT, out);
    } else {
        unsigned* cnt = (unsigned*)(ws + OFF_TOT);
        hipMemsetAsync(cnt, 0, (size_t)NB * 3 * NBINS * sizeof(unsigned), stream);
        count_fb_kernel<<<NB * 3 * SPLIT, 1024, 0, stream>>>(bins, cnt);
        scatter_kernel<<<NB * 3 * NC, 1024, 0, stream>>>(bins, feat, cnt, out);
    }
}